// Round 8
// baseline (587.835 us; speedup 1.0000x reference)
//
#include <hip/hip_runtime.h>

#define N_NODES  100000
#define N_EDGES  1600000
#define N_GRAPHS 512
#define HID      128

typedef unsigned int  uint;
typedef unsigned short ushort;
typedef __attribute__((ext_vector_type(8))) short  short8;   // 8 bf16 (4 VGPRs)
typedef __attribute__((ext_vector_type(4))) float  f32x4;

__device__ inline float bflo(uint u) { return __uint_as_float(u << 16); }
__device__ inline float bfhi(uint u) { return __uint_as_float(u & 0xffff0000u); }
__device__ inline ushort f2bf(float f) {
    uint u = __float_as_uint(f);
    return (ushort)((u + 0x7fffu + ((u >> 16) & 1u)) >> 16);   // RNE
}
__device__ inline float bf2f(ushort s) { return __uint_as_float(((uint)s) << 16); }
__device__ inline uint pk(float a, float b) {
    return (uint)f2bf(a) | ((uint)f2bf(b) << 16);
}

// ---------------- prep: cvt x|temb -> bf16 | zero cnt | pack W | graph boundaries ----------------
// blocks: [0,6250) cvt_x, [6250,9375) cvt_temb, [9375,9766) zero, [9766,9990) pack, [9990,10381) boundary
__global__ __launch_bounds__(256)
void prep_kernel(const float* __restrict__ x, ushort* __restrict__ xb,
                 const float* __restrict__ temb, ushort* __restrict__ tembb,
                 int* __restrict__ cnt,
                 const float* __restrict__ Wt, const float* __restrict__ W1,
                 const float* __restrict__ Ws, ushort* __restrict__ packed,
                 const int* __restrict__ batch, int* __restrict__ gstart) {
    int b = blockIdx.x;
    int t = threadIdx.x;
    if (b < 6250) {                         // cvt x (N*64 floats, 4/thread)
        int i = (b * 256 + t) * 4;
        float4 f = *(const float4*)(x + i);
        uint2 o; o.x = pk(f.x, f.y); o.y = pk(f.z, f.w);
        *(uint2*)(xb + i) = o;
    } else if (b < 9375) {                  // cvt temb (N*128 floats, 16/thread)
        long i = ((long)(b - 6250) * 256 + t) * 16;
        if (i >= (long)N_NODES * 128) return;
#pragma unroll
        for (int k = 0; k < 4; ++k) {
            float4 f = *(const float4*)(temb + i + k * 4);
            uint2 o; o.x = pk(f.x, f.y); o.y = pk(f.z, f.w);
            *(uint2*)(tembb + i + k * 4) = o;
        }
    } else if (b < 9766) {                  // zero cnt
        int i = (b - 9375) * 256 + t;
        if (i < N_NODES) cnt[i] = 0;
    } else if (b < 9990) {                  // pack weights into MFMA B-frag order
        int tid = (b - 9766) * 256 + t;
        const float* src; int p; ushort* dst;
        if (tid < 16384)      { src = Wt;         p = tid;         dst = packed; }
        else if (tid < 24576) { src = W1;         p = tid - 16384; dst = packed + 16384; }
        else if (tid < 40960) { src = Ws;         p = tid - 24576; dst = packed + 24576; }
        else                  { src = Ws + 16384; p = tid - 40960; dst = packed + 40960; }
        int j  = p & 7;
        int L  = (p >> 3) & 63;
        int cb = (p >> 9) & 7;
        int s  = p >> 12;
        int k  = s * 32 + (L >> 4) * 8 + j;
        int n  = cb * 16 + (L & 15);
        dst[p] = f2bf(src[k * 128 + n]);
    } else {                                // graph boundary scan (batch sorted)
        int i = (b - 9990) * 256 + t;
        if (i >= N_NODES) return;
        int bb = batch[i];
        int prev = (i == 0) ? -1 : batch[i - 1];
        for (int g = prev + 1; g <= bb; ++g) gstart[g] = i;
        if (i == N_NODES - 1) {
            for (int g = bb + 1; g <= N_GRAPHS; ++g) gstart[g] = N_NODES;
        }
    }
}

// ---------------- CSR build ----------------

__global__ void hist_kernel(const int* __restrict__ dst, int* __restrict__ cnt, int e) {
    int i = blockIdx.x * blockDim.x + threadIdx.x;
    if (i < e) atomicAdd(&cnt[dst[i]], 1);
}

__global__ __launch_bounds__(256)
void scanA(const int* __restrict__ cnt, int* __restrict__ row_ptr,
           int* __restrict__ partial, float* __restrict__ dinv, int n) {
    __shared__ int ssum[256];
    int t = threadIdx.x;
    int base = blockIdx.x * 1024 + t * 4;
    int v0 = 0, v1 = 0, v2 = 0, v3 = 0;
    if (base     < n) v0 = cnt[base];
    if (base + 1 < n) v1 = cnt[base + 1];
    if (base + 2 < n) v2 = cnt[base + 2];
    if (base + 3 < n) v3 = cnt[base + 3];
    if (base     < n) dinv[base]     = rsqrtf((float)(v0 + 1));
    if (base + 1 < n) dinv[base + 1] = rsqrtf((float)(v1 + 1));
    if (base + 2 < n) dinv[base + 2] = rsqrtf((float)(v2 + 1));
    if (base + 3 < n) dinv[base + 3] = rsqrtf((float)(v3 + 1));
    int tot = v0 + v1 + v2 + v3;
    ssum[t] = tot;
    __syncthreads();
    for (int off = 1; off < 256; off <<= 1) {
        int x = (t >= off) ? ssum[t - off] : 0;
        __syncthreads();
        ssum[t] += x;
        __syncthreads();
    }
    int excl = ssum[t] - tot;
    if (base     < n) row_ptr[base]     = excl;
    if (base + 1 < n) row_ptr[base + 1] = excl + v0;
    if (base + 2 < n) row_ptr[base + 2] = excl + v0 + v1;
    if (base + 3 < n) row_ptr[base + 3] = excl + v0 + v1 + v2;
    if (t == 255) partial[blockIdx.x] = ssum[255];
}

__global__ __launch_bounds__(256)
void scanC(int* __restrict__ row_ptr, const int* __restrict__ partial,
           int* __restrict__ cursor, int n, int nb) {
    __shared__ int sp[128];
    int t = threadIdx.x;
    if (t < 128) sp[t] = (t < nb) ? partial[t] : 0;
    __syncthreads();
    for (int off = 1; off < 128; off <<= 1) {
        int x = (t >= off && t < 128) ? sp[t - off] : 0;
        __syncthreads();
        if (t < 128) sp[t] += x;
        __syncthreads();
    }
    int i = blockIdx.x * 256 + t;
    if (i < n) {
        int bb = i >> 10;
        int off = (bb == 0) ? 0 : sp[bb - 1];
        int v = row_ptr[i] + off;
        row_ptr[i] = v;
        cursor[i]  = v;
    }
    if (blockIdx.x == 0 && t == 0) row_ptr[n] = sp[nb - 1];
}

// dst-partitioned fill: partition = blockIdx%8 (round-robin XCD) owns a 12500-node
// dst range, so edge-array lines are written by one XCD only (kills the 8x
// cross-XCD partial-line write-back amplification seen in R5/R7).
#define FILL_CHUNKS 120
__global__ __launch_bounds__(256)
void fill_part(const int* __restrict__ src, const int* __restrict__ dst,
               const float* __restrict__ dinv, int* __restrict__ cursor,
               int2* __restrict__ edge, int e) {
    int pr = blockIdx.x & 7;
    int q  = blockIdx.x >> 3;
    int lo = (int)((long)e * q / FILL_CHUNKS);
    int hi = (int)((long)e * (q + 1) / FILL_CHUNKS);
    int plo = pr * (N_NODES / 8), phi = plo + (N_NODES / 8);
    for (int i = lo + threadIdx.x; i < hi; i += 256) {
        int d = dst[i];
        if (d >= plo && d < phi) {
            int s = src[i];
            int pos = atomicAdd(&cursor[d], 1);
            int2 ed; ed.x = s; ed.y = __float_as_int(dinv[s] * dinv[d]);
            edge[pos] = ed;
        }
    }
}

// ---------------- fused GCN conv ----------------
// O[v,:] = relu( agg(H)[v,:] @ W + b )  [+ relu( tembb[v,:] @ Wt + bt ) if TEMB]
template <int K, bool TEMB>
__global__ __launch_bounds__(256)
void fused_conv(const ushort* __restrict__ H, const int* __restrict__ rp,
                const int2* __restrict__ edge, const float* __restrict__ dinv,
                const ushort* __restrict__ Wp, const float* __restrict__ bias,
                const ushort* __restrict__ tembb, const ushort* __restrict__ Wtp,
                const float* __restrict__ bias_t, ushort* __restrict__ O, int ntiles) {
    constexpr int LPR  = K / 8;       // lanes per gathered row (uint4 = 8 feats/lane)
    constexpr int G    = 64 / LPR;    // edge groups per wave
    constexpr int LROW = 136;         // LDS row stride in shorts
    __shared__ __align__(16) ushort sA[4][16 * LROW];
    const int wave = threadIdx.x >> 6;
    const int lane = threadIdx.x & 63;
    const int tile = blockIdx.x * 4 + wave;
    if (tile >= ntiles) return;       // per-wave LDS, no barriers: safe
    const int row0 = tile * 16;
    const int g  = lane / LPR;
    const int fq = lane % LPR;
    ushort* myA = sA[wave];

    // ---- phase 1: gather 16 rows into LDS (4-deep unrolled edge loop) ----
    for (int r = 0; r < 16; ++r) {
        int v = row0 + r;
        int s = rp[v], e = rp[v + 1];
        float a0 = 0.f, a1 = 0.f, a2 = 0.f, a3 = 0.f;
        float a4 = 0.f, a5 = 0.f, a6 = 0.f, a7 = 0.f;
        if (g == 0) {   // self-loop term
            uint4 xv = *(const uint4*)(H + (size_t)v * K + fq * 8);
            float dv = dinv[v]; float w0 = dv * dv;
            a0 = w0 * bflo(xv.x); a1 = w0 * bfhi(xv.x);
            a2 = w0 * bflo(xv.y); a3 = w0 * bfhi(xv.y);
            a4 = w0 * bflo(xv.z); a5 = w0 * bfhi(xv.z);
            a6 = w0 * bflo(xv.w); a7 = w0 * bfhi(xv.w);
        }
        int iters = (e - s + G - 1) / G;   // wave-uniform
        int j = s + g;
        for (int i = 0; i < iters; i += 4, j += 4 * G) {
            int jv[4]; int2 ev[4]; uint4 hv[4]; float wv[4];
#pragma unroll
            for (int u = 0; u < 4; ++u) {
                jv[u] = j + u * G;
                int jj = (jv[u] < e) ? jv[u] : e - 1;   // iters>0 => e>s => e-1 valid
                ev[u] = edge[jj];
            }
#pragma unroll
            for (int u = 0; u < 4; ++u) {
                wv[u] = (jv[u] < e) ? __int_as_float(ev[u].y) : 0.f;
                hv[u] = *(const uint4*)(H + (size_t)ev[u].x * K + fq * 8);
            }
#pragma unroll
            for (int u = 0; u < 4; ++u) {
                a0 += wv[u] * bflo(hv[u].x); a1 += wv[u] * bfhi(hv[u].x);
                a2 += wv[u] * bflo(hv[u].y); a3 += wv[u] * bfhi(hv[u].y);
                a4 += wv[u] * bflo(hv[u].z); a5 += wv[u] * bfhi(hv[u].z);
                a6 += wv[u] * bflo(hv[u].w); a7 += wv[u] * bfhi(hv[u].w);
            }
        }
        // reduce across edge groups
        for (int d = LPR; d < 64; d <<= 1) {
            a0 += __shfl_xor(a0, d); a1 += __shfl_xor(a1, d);
            a2 += __shfl_xor(a2, d); a3 += __shfl_xor(a3, d);
            a4 += __shfl_xor(a4, d); a5 += __shfl_xor(a5, d);
            a6 += __shfl_xor(a6, d); a7 += __shfl_xor(a7, d);
        }
        if (g == 0) {
            uint4 o;
            o.x = pk(a0, a1); o.y = pk(a2, a3);
            o.z = pk(a4, a5); o.w = pk(a6, a7);
            *(uint4*)(myA + r * LROW + fq * 8) = o;
        }
    }

    // ---- phase 2: MFMA (A from LDS, B packed from global/L2) ----
    const int m = lane & 15, q = lane >> 4;
    f32x4 acc[8];
#pragma unroll
    for (int cb = 0; cb < 8; ++cb) acc[cb] = {0.f, 0.f, 0.f, 0.f};
    constexpr int S = K / 32;
#pragma unroll
    for (int s = 0; s < S; ++s) {
        short8 a = *(const short8*)(myA + m * LROW + s * 32 + q * 8);
#pragma unroll
        for (int cb = 0; cb < 8; ++cb) {
            short8 b = *(const short8*)(Wp + (size_t)((s * 8 + cb) * 64 + lane) * 8);
            acc[cb] = __builtin_amdgcn_mfma_f32_16x16x32_bf16(a, b, acc[cb], 0, 0, 0);
        }
    }

    // ---- phase 2b (TEMB): second MFMA chain, A = tembb bf16 tile (dense rows) ----
    f32x4 acc2[TEMB ? 8 : 1];
    if (TEMB) {
#pragma unroll
        for (int cb = 0; cb < 8; ++cb) acc2[cb] = {0.f, 0.f, 0.f, 0.f};
        const ushort* Arow = tembb + (size_t)(row0 + m) * 128 + q * 8;
#pragma unroll
        for (int s = 0; s < 4; ++s) {
            short8 a = *(const short8*)(Arow + s * 32);
#pragma unroll
            for (int cb = 0; cb < 8; ++cb) {
                short8 b = *(const short8*)(Wtp + (size_t)((s * 8 + cb) * 64 + lane) * 8);
                acc2[cb] = __builtin_amdgcn_mfma_f32_16x16x32_bf16(a, b, acc2[cb], 0, 0, 0);
            }
        }
    }

    // ---- phase 3: epilogue into LDS, coalesced store ----
    // C/D layout: col = lane&15, row = (lane>>4)*4 + r
#pragma unroll
    for (int cb = 0; cb < 8; ++cb) {
        int colc = cb * 16 + m;
        float bv = bias[colc];
        float bt2 = TEMB ? bias_t[colc] : 0.f;
#pragma unroll
        for (int r = 0; r < 4; ++r) {
            int row = q * 4 + r;
            float v = fmaxf(acc[cb][r] + bv, 0.0f);
            if (TEMB) v += fmaxf(acc2[cb][r] + bt2, 0.0f);
            myA[row * LROW + colc] = f2bf(v);
        }
    }
#pragma unroll
    for (int i = 0; i < 4; ++i) {
        int srow = i * 4 + (lane >> 4);
        int scol = (lane & 15) * 8;
        *(short8*)(O + (size_t)(row0 + srow) * 128 + scol) =
            *(const short8*)(myA + srow * LROW + scol);
    }
}

// ---------------- pooling + output head (fused) ----------------

__global__ void pool_out(const ushort* __restrict__ h, const int* __restrict__ gstart,
                         const float* __restrict__ Wo, const float* __restrict__ bo,
                         float* __restrict__ out) {
    int g = blockIdx.x;
    int t = threadIdx.x;          // 256
    int f2 = t & 63;
    int half = t >> 6;
    int s = gstart[g], e = gstart[g + 1];
    float ax = 0.f, ay = 0.f;
    for (int i = s + half; i < e; i += 4) {
        uint u = *(const uint*)(h + (size_t)i * HID + f2 * 2);
        ax += bflo(u); ay += bfhi(u);
    }
    __shared__ float red[2][256];
    __shared__ float P[128];
    red[0][t] = ax; red[1][t] = ay;
    __syncthreads();
    if (half == 0) {
        for (int k = 1; k < 4; ++k) { ax += red[0][f2 + 64 * k]; ay += red[1][f2 + 64 * k]; }
        float c = (float)((e - s) < 1 ? 1 : (e - s));
        P[f2 * 2]     = ax / c;
        P[f2 * 2 + 1] = ay / c;
    }
    __syncthreads();
    if (t < 16) {
        float acc = bo[t];
        for (int k = 0; k < HID; ++k) acc += P[k] * Wo[k * 16 + t];
        out[g * 16 + t] = acc;
    }
}

// ---------------- launch ----------------

extern "C" void kernel_launch(void* const* d_in, const int* in_sizes, int n_in,
                              void* d_out, int out_size, void* d_ws, size_t ws_size,
                              hipStream_t stream) {
    const float* x       = (const float*)d_in[0];
    const int*   ei      = (const int*)d_in[1];
    const float* temb_in = (const float*)d_in[2];
    const int*   batch   = (const int*)d_in[3];
    const float* Wt      = (const float*)d_in[4];
    const float* bt      = (const float*)d_in[5];
    const float* W1      = (const float*)d_in[6];
    const float* b1      = (const float*)d_in[7];
    const float* Ws      = (const float*)d_in[8];
    const float* bs      = (const float*)d_in[9];
    const float* Wo      = (const float*)d_in[10];
    const float* bo      = (const float*)d_in[11];
    float* out = (float*)d_out;

    const int N = N_NODES, E = N_EDGES;
    const int* src = ei;
    const int* dst = ei + E;

    char* p = (char*)d_ws;
    auto carve = [&](size_t bytes) -> void* {
        void* r = (void*)p;
        p += (bytes + 255) & ~(size_t)255;
        return r;
    };
    int*    cnt     = (int*)carve((size_t)N * 4);
    float*  dinv    = (float*)carve((size_t)N * 4);
    int*    row_ptr = (int*)carve((size_t)(N + 1) * 4);
    int*    cursor  = (int*)carve((size_t)N * 4);
    int*    partial = (int*)carve((size_t)128 * 4);
    int2*   edge    = (int2*)carve((size_t)E * 8);
    int*    gstart  = (int*)carve((size_t)(N_GRAPHS + 1) * 4);
    ushort* packed  = (ushort*)carve((size_t)57344 * 2);
    ushort* xb      = (ushort*)carve((size_t)N * 64 * 2);
    ushort* tembb   = (ushort*)carve((size_t)N * 128 * 2);
    ushort* H1      = (ushort*)carve((size_t)N * 128 * 2);  // also holds H3
    ushort* H2      = (ushort*)carve((size_t)N * 128 * 2);

    const ushort* Wtp  = packed;
    const ushort* W1p  = packed + 16384;
    const ushort* Ws0p = packed + 24576;
    const ushort* Ws1p = packed + 40960;

    const int ntiles = N / 16;            // 6250
    const int gblk   = (ntiles + 3) / 4;  // 1563
    const int nb     = (N + 1023) / 1024; // 98

    // prep: cvt x | cvt temb | zero cnt | pack W | boundaries   (one launch)
    prep_kernel<<<10381, 256, 0, stream>>>(x, xb, temb_in, tembb, cnt, Wt, W1, Ws,
                                           packed, batch, gstart);

    // CSR build
    hist_kernel<<<(E + 255) / 256, 256, 0, stream>>>(dst, cnt, E);
    scanA<<<nb, 256, 0, stream>>>(cnt, row_ptr, partial, dinv, N);
    scanC<<<(N + 255) / 256, 256, 0, stream>>>(row_ptr, partial, cursor, N, nb);
    fill_part<<<8 * FILL_CHUNKS, 256, 0, stream>>>(src, dst, dinv, cursor, edge, E);

    // conv1 (+fused temb layer): H1 = relu(agg(x)@W1+b1) + relu(tembb@Wt+bt)
    fused_conv<64, true><<<gblk, 256, 0, stream>>>(xb, row_ptr, edge, dinv, W1p, b1,
                                                   tembb, Wtp, bt, H1, ntiles);
    // conv2: H2 = relu(agg(H1)@Ws0 + bs0)
    fused_conv<128, false><<<gblk, 256, 0, stream>>>(H1, row_ptr, edge, dinv, Ws0p, bs,
                                                     nullptr, nullptr, nullptr, H2, ntiles);
    // conv3: H3(=H1) = relu(agg(H2)@Ws1 + bs1)
    fused_conv<128, false><<<gblk, 256, 0, stream>>>(H2, row_ptr, edge, dinv, Ws1p, bs + 128,
                                                     nullptr, nullptr, nullptr, H1, ntiles);

    // pool + head (fused)
    pool_out<<<N_GRAPHS, 256, 0, stream>>>(H1, gstart, Wo, bo, out);
}

// Round 10
// 546.300 us; speedup vs baseline: 1.0760x; 1.0760x over previous
//
#include <hip/hip_runtime.h>

#define N_NODES  100000
#define N_EDGES  1600000
#define N_GRAPHS 512
#define HID      128

typedef unsigned int  uint;
typedef unsigned char uchar;
typedef unsigned short ushort;
typedef __attribute__((ext_vector_type(8))) short  short8;   // 8 bf16 (4 VGPRs)
typedef __attribute__((ext_vector_type(4))) float  f32x4;
typedef __attribute__((ext_vector_type(2))) float  f32x2;

__device__ inline float bflo(uint u) { return __uint_as_float(u << 16); }
__device__ inline float bfhi(uint u) { return __uint_as_float(u & 0xffff0000u); }
__device__ inline ushort f2bf(float f) {
    uint u = __float_as_uint(f);
    return (ushort)((u + 0x7fffu + ((u >> 16) & 1u)) >> 16);   // RNE
}
__device__ inline uint pk(float a, float b) {
    return (uint)f2bf(a) | ((uint)f2bf(b) << 16);
}

__device__ inline void acc8_bf16(uint4 hv, float w, float* a) {
    a[0] += w * bflo(hv.x); a[1] += w * bfhi(hv.x);
    a[2] += w * bflo(hv.y); a[3] += w * bfhi(hv.y);
    a[4] += w * bflo(hv.z); a[5] += w * bfhi(hv.z);
    a[6] += w * bflo(hv.w); a[7] += w * bfhi(hv.w);
}
__device__ inline void acc8_fp8(uint2 hv, float w, float* a) {
    f32x2 p0 = __builtin_amdgcn_cvt_pk_f32_fp8((int)hv.x, false);
    f32x2 p1 = __builtin_amdgcn_cvt_pk_f32_fp8((int)hv.x, true);
    f32x2 p2 = __builtin_amdgcn_cvt_pk_f32_fp8((int)hv.y, false);
    f32x2 p3 = __builtin_amdgcn_cvt_pk_f32_fp8((int)hv.y, true);
    a[0] += w * p0.x; a[1] += w * p0.y; a[2] += w * p1.x; a[3] += w * p1.y;
    a[4] += w * p2.x; a[5] += w * p2.y; a[6] += w * p3.x; a[7] += w * p3.y;
}

// ---------------- prep: cvt x|temb -> bf16 | zero cnt | pack W | graph boundaries ----------------
// blocks: [0,6250) cvt_x, [6250,9375) cvt_temb, [9375,9766) zero, [9766,9990) pack, [9990,10381) boundary
__global__ __launch_bounds__(256)
void prep_kernel(const float* __restrict__ x, ushort* __restrict__ xb,
                 const float* __restrict__ temb, ushort* __restrict__ tembb,
                 int* __restrict__ cnt,
                 const float* __restrict__ Wt, const float* __restrict__ W1,
                 const float* __restrict__ Ws, ushort* __restrict__ packed,
                 const int* __restrict__ batch, int* __restrict__ gstart) {
    int b = blockIdx.x;
    int t = threadIdx.x;
    if (b < 6250) {                         // cvt x (N*64 floats, 4/thread)
        int i = (b * 256 + t) * 4;
        float4 f = *(const float4*)(x + i);
        uint2 o; o.x = pk(f.x, f.y); o.y = pk(f.z, f.w);
        *(uint2*)(xb + i) = o;
    } else if (b < 9375) {                  // cvt temb (N*128 floats, 16/thread)
        long i = ((long)(b - 6250) * 256 + t) * 16;
        if (i >= (long)N_NODES * 128) return;
#pragma unroll
        for (int k = 0; k < 4; ++k) {
            float4 f = *(const float4*)(temb + i + k * 4);
            uint2 o; o.x = pk(f.x, f.y); o.y = pk(f.z, f.w);
            *(uint2*)(tembb + i + k * 4) = o;
        }
    } else if (b < 9766) {                  // zero cnt
        int i = (b - 9375) * 256 + t;
        if (i < N_NODES) cnt[i] = 0;
    } else if (b < 9990) {                  // pack weights into MFMA B-frag order
        int tid = (b - 9766) * 256 + t;
        const float* src; int p; ushort* dst;
        if (tid < 16384)      { src = Wt;         p = tid;         dst = packed; }
        else if (tid < 24576) { src = W1;         p = tid - 16384; dst = packed + 16384; }
        else if (tid < 40960) { src = Ws;         p = tid - 24576; dst = packed + 24576; }
        else                  { src = Ws + 16384; p = tid - 40960; dst = packed + 40960; }
        int j  = p & 7;
        int L  = (p >> 3) & 63;
        int cb = (p >> 9) & 7;
        int s  = p >> 12;
        int k  = s * 32 + (L >> 4) * 8 + j;
        int n  = cb * 16 + (L & 15);
        dst[p] = f2bf(src[k * 128 + n]);
    } else {                                // graph boundary scan (batch sorted)
        int i = (b - 9990) * 256 + t;
        if (i >= N_NODES) return;
        int bb = batch[i];
        int prev = (i == 0) ? -1 : batch[i - 1];
        for (int g = prev + 1; g <= bb; ++g) gstart[g] = i;
        if (i == N_NODES - 1) {
            for (int g = bb + 1; g <= N_GRAPHS; ++g) gstart[g] = N_NODES;
        }
    }
}

// ---------------- CSR build ----------------

__global__ void hist_kernel(const int4* __restrict__ dst4, int* __restrict__ cnt, int e4) {
    int i = blockIdx.x * blockDim.x + threadIdx.x;
    if (i >= e4) return;
    int4 d = dst4[i];
    atomicAdd(&cnt[d.x], 1);
    atomicAdd(&cnt[d.y], 1);
    atomicAdd(&cnt[d.z], 1);
    atomicAdd(&cnt[d.w], 1);
}

__global__ __launch_bounds__(256)
void scanA(const int* __restrict__ cnt, int* __restrict__ row_ptr,
           int* __restrict__ partial, float* __restrict__ dinv, int n) {
    __shared__ int ssum[256];
    int t = threadIdx.x;
    int base = blockIdx.x * 1024 + t * 4;
    int v0 = 0, v1 = 0, v2 = 0, v3 = 0;
    if (base     < n) v0 = cnt[base];
    if (base + 1 < n) v1 = cnt[base + 1];
    if (base + 2 < n) v2 = cnt[base + 2];
    if (base + 3 < n) v3 = cnt[base + 3];
    if (base     < n) dinv[base]     = rsqrtf((float)(v0 + 1));
    if (base + 1 < n) dinv[base + 1] = rsqrtf((float)(v1 + 1));
    if (base + 2 < n) dinv[base + 2] = rsqrtf((float)(v2 + 1));
    if (base + 3 < n) dinv[base + 3] = rsqrtf((float)(v3 + 1));
    int tot = v0 + v1 + v2 + v3;
    ssum[t] = tot;
    __syncthreads();
    for (int off = 1; off < 256; off <<= 1) {
        int x = (t >= off) ? ssum[t - off] : 0;
        __syncthreads();
        ssum[t] += x;
        __syncthreads();
    }
    int excl = ssum[t] - tot;
    if (base     < n) row_ptr[base]     = excl;
    if (base + 1 < n) row_ptr[base + 1] = excl + v0;
    if (base + 2 < n) row_ptr[base + 2] = excl + v0 + v1;
    if (base + 3 < n) row_ptr[base + 3] = excl + v0 + v1 + v2;
    if (t == 255) partial[blockIdx.x] = ssum[255];
}

__global__ __launch_bounds__(256)
void scanC(int* __restrict__ row_ptr, const int* __restrict__ partial,
           int* __restrict__ cursor, int n, int nb) {
    __shared__ int sp[128];
    int t = threadIdx.x;
    if (t < 128) sp[t] = (t < nb) ? partial[t] : 0;
    __syncthreads();
    for (int off = 1; off < 128; off <<= 1) {
        int x = (t >= off && t < 128) ? sp[t - off] : 0;
        __syncthreads();
        if (t < 128) sp[t] += x;
        __syncthreads();
    }
    int i = blockIdx.x * 256 + t;
    if (i < n) {
        int bb = i >> 10;
        int off = (bb == 0) ? 0 : sp[bb - 1];
        int v = row_ptr[i] + off;
        row_ptr[i] = v;
        cursor[i]  = v;
    }
    if (blockIdx.x == 0 && t == 0) row_ptr[n] = sp[nb - 1];
}

// fill CSR with interleaved edge record {src, bits(norm)}  (8B scatter, R7-proven)
__global__ void fill_kernel(const int* __restrict__ src, const int* __restrict__ dst,
                            const float* __restrict__ dinv, int* __restrict__ cursor,
                            int2* __restrict__ edge, int e) {
    int i = blockIdx.x * blockDim.x + threadIdx.x;
    if (i >= e) return;
    int s = src[i], d = dst[i];
    int pos = atomicAdd(&cursor[d], 1);
    int2 ed; ed.x = s; ed.y = __float_as_int(dinv[s] * dinv[d]);
    edge[pos] = ed;
}

// ---------------- fused GCN conv ----------------
// O[v,:] = relu( agg(H)[v,:] @ W + b )  [+ relu( tembb[v,:] @ Wt + bt ) if TEMB]
// SRC8: gather source rows are fp8 e4m3.  OUT8: output written as fp8 e4m3.
template <int K, bool TEMB, bool SRC8, bool OUT8>
__global__ __launch_bounds__(256)
void fused_conv(const void* __restrict__ Hv, const int* __restrict__ rp,
                const int2* __restrict__ edge, const float* __restrict__ dinv,
                const ushort* __restrict__ Wp, const float* __restrict__ bias,
                const ushort* __restrict__ tembb, const ushort* __restrict__ Wtp,
                const float* __restrict__ bias_t, void* __restrict__ Ov, int ntiles) {
    constexpr int LPR  = K / 8;       // lanes per gathered row (8 feats/lane)
    constexpr int G    = 64 / LPR;    // edge groups per wave
    constexpr int LROW = 136;         // LDS row stride in shorts (bf16 staging)
    __shared__ __align__(16) ushort sA[4][16 * LROW];
    const int wave = threadIdx.x >> 6;
    const int lane = threadIdx.x & 63;
    const int tile = blockIdx.x * 4 + wave;
    if (tile >= ntiles) return;       // per-wave LDS, no barriers: safe
    const int row0 = tile * 16;
    const int g  = lane / LPR;
    const int fq = lane % LPR;
    ushort* myA = sA[wave];
    const ushort* Hb = (const ushort*)Hv;
    const uchar*  H8 = (const uchar*)Hv;

    // ---- phase 1: gather 16 rows into LDS (4-deep unrolled edge loop) ----
    for (int r = 0; r < 16; ++r) {
        int v = row0 + r;
        int s = rp[v], e = rp[v + 1];
        float a[8] = {0.f, 0.f, 0.f, 0.f, 0.f, 0.f, 0.f, 0.f};
        if (g == 0) {   // self-loop term
            float dv = dinv[v]; float w0 = dv * dv;
            if constexpr (!SRC8) {
                uint4 xv = *(const uint4*)(Hb + (size_t)v * K + fq * 8);
                acc8_bf16(xv, w0, a);
            } else {
                uint2 xv = *(const uint2*)(H8 + (size_t)v * K + fq * 8);
                acc8_fp8(xv, w0, a);
            }
        }
        int iters = (e - s + G - 1) / G;   // wave-uniform
        int j = s + g;
        for (int i = 0; i < iters; i += 4, j += 4 * G) {
            int jv[4]; int2 ev[4]; float wv[4];
#pragma unroll
            for (int u = 0; u < 4; ++u) {
                jv[u] = j + u * G;
                int jj = (jv[u] < e) ? jv[u] : e - 1;   // iters>0 => e>s => e-1 valid
                ev[u] = edge[jj];
            }
            if constexpr (!SRC8) {
                uint4 hv[4];
#pragma unroll
                for (int u = 0; u < 4; ++u) {
                    wv[u] = (jv[u] < e) ? __int_as_float(ev[u].y) : 0.f;
                    hv[u] = *(const uint4*)(Hb + (size_t)ev[u].x * K + fq * 8);
                }
#pragma unroll
                for (int u = 0; u < 4; ++u) acc8_bf16(hv[u], wv[u], a);
            } else {
                uint2 hv[4];
#pragma unroll
                for (int u = 0; u < 4; ++u) {
                    wv[u] = (jv[u] < e) ? __int_as_float(ev[u].y) : 0.f;
                    hv[u] = *(const uint2*)(H8 + (size_t)ev[u].x * K + fq * 8);
                }
#pragma unroll
                for (int u = 0; u < 4; ++u) acc8_fp8(hv[u], wv[u], a);
            }
        }
        // reduce across edge groups
        for (int d = LPR; d < 64; d <<= 1) {
#pragma unroll
            for (int k = 0; k < 8; ++k) a[k] += __shfl_xor(a[k], d);
        }
        if (g == 0) {
            uint4 o;
            o.x = pk(a[0], a[1]); o.y = pk(a[2], a[3]);
            o.z = pk(a[4], a[5]); o.w = pk(a[6], a[7]);
            *(uint4*)(myA + r * LROW + fq * 8) = o;
        }
    }

    // ---- phase 2: MFMA (A from LDS, B packed from global/L2) ----
    const int m = lane & 15, q = lane >> 4;
    f32x4 acc[8];
#pragma unroll
    for (int cb = 0; cb < 8; ++cb) acc[cb] = {0.f, 0.f, 0.f, 0.f};
    constexpr int S = K / 32;
#pragma unroll
    for (int s = 0; s < S; ++s) {
        short8 av = *(const short8*)(myA + m * LROW + s * 32 + q * 8);
#pragma unroll
        for (int cb = 0; cb < 8; ++cb) {
            short8 b = *(const short8*)(Wp + (size_t)((s * 8 + cb) * 64 + lane) * 8);
            acc[cb] = __builtin_amdgcn_mfma_f32_16x16x32_bf16(av, b, acc[cb], 0, 0, 0);
        }
    }

    // ---- phase 2b (TEMB): second MFMA chain, A = tembb bf16 tile (dense rows) ----
    f32x4 acc2[TEMB ? 8 : 1];
    if (TEMB) {
#pragma unroll
        for (int cb = 0; cb < 8; ++cb) acc2[cb] = {0.f, 0.f, 0.f, 0.f};
        const ushort* Arow = tembb + (size_t)(row0 + m) * 128 + q * 8;
#pragma unroll
        for (int s = 0; s < 4; ++s) {
            short8 av = *(const short8*)(Arow + s * 32);
#pragma unroll
            for (int cb = 0; cb < 8; ++cb) {
                short8 b = *(const short8*)(Wtp + (size_t)((s * 8 + cb) * 64 + lane) * 8);
                acc2[cb] = __builtin_amdgcn_mfma_f32_16x16x32_bf16(av, b, acc2[cb], 0, 0, 0);
            }
        }
    }

    // ---- phase 3: epilogue into LDS, coalesced store ----
    // C/D layout: col = lane&15, row = (lane>>4)*4 + r
    if constexpr (!OUT8) {
        ushort* Ob = (ushort*)Ov;
#pragma unroll
        for (int cb = 0; cb < 8; ++cb) {
            int colc = cb * 16 + m;
            float bv = bias[colc];
            float bt2 = TEMB ? bias_t[colc] : 0.f;
#pragma unroll
            for (int r = 0; r < 4; ++r) {
                int row = q * 4 + r;
                float v = fmaxf(acc[cb][r] + bv, 0.0f);
                if (TEMB) v += fmaxf(acc2[cb][r] + bt2, 0.0f);
                myA[row * LROW + colc] = f2bf(v);
            }
        }
#pragma unroll
        for (int i = 0; i < 4; ++i) {
            int srow = i * 4 + (lane >> 4);
            int scol = (lane & 15) * 8;
            *(short8*)(Ob + (size_t)(row0 + srow) * 128 + scol) =
                *(const short8*)(myA + srow * LROW + scol);
        }
    } else {
        uchar* st8 = (uchar*)myA;           // byte staging, row stride 136 B
        uchar* Ob = (uchar*)Ov;
#pragma unroll
        for (int cb = 0; cb < 8; ++cb) {
            int colc = cb * 16 + m;
            float bv = bias[colc];
            float bt2 = TEMB ? bias_t[colc] : 0.f;
#pragma unroll
            for (int r = 0; r < 4; ++r) {
                int row = q * 4 + r;
                float v = fmaxf(acc[cb][r] + bv, 0.0f);
                if (TEMB) v += fmaxf(acc2[cb][r] + bt2, 0.0f);
                int enc = __builtin_amdgcn_cvt_pk_fp8_f32(v, v, 0, false);
                st8[row * 136 + colc] = (uchar)(enc & 0xff);
            }
        }
        // 16 rows * 128 B = 2048 B; 64 lanes * 8 B = 512 B/iter -> 4 iters (R9 bug: was 2)
#pragma unroll
        for (int i = 0; i < 4; ++i) {
            int idx = i * 64 + lane;        // [0,256)
            int srow = idx >> 4;            // [0,16)
            int soff = (idx & 15) * 8;      // [0,128) step 8
            *(uint2*)(Ob + (size_t)(row0 + srow) * 128 + soff) =
                *(const uint2*)(st8 + srow * 136 + soff);
        }
    }
}

// ---------------- pooling + output head (fused) ----------------

__global__ void pool_out(const ushort* __restrict__ h, const int* __restrict__ gstart,
                         const float* __restrict__ Wo, const float* __restrict__ bo,
                         float* __restrict__ out) {
    int g = blockIdx.x;
    int t = threadIdx.x;          // 256
    int f2 = t & 63;
    int half = t >> 6;
    int s = gstart[g], e = gstart[g + 1];
    float ax = 0.f, ay = 0.f;
    for (int i = s + half; i < e; i += 4) {
        uint u = *(const uint*)(h + (size_t)i * HID + f2 * 2);
        ax += bflo(u); ay += bfhi(u);
    }
    __shared__ float red[2][256];
    __shared__ float P[128];
    red[0][t] = ax; red[1][t] = ay;
    __syncthreads();
    if (half == 0) {
        for (int k = 1; k < 4; ++k) { ax += red[0][f2 + 64 * k]; ay += red[1][f2 + 64 * k]; }
        float c = (float)((e - s) < 1 ? 1 : (e - s));
        P[f2 * 2]     = ax / c;
        P[f2 * 2 + 1] = ay / c;
    }
    __syncthreads();
    if (t < 16) {
        float acc = bo[t];
        for (int k = 0; k < HID; ++k) acc += P[k] * Wo[k * 16 + t];
        out[g * 16 + t] = acc;
    }
}

// ---------------- launch ----------------

extern "C" void kernel_launch(void* const* d_in, const int* in_sizes, int n_in,
                              void* d_out, int out_size, void* d_ws, size_t ws_size,
                              hipStream_t stream) {
    const float* x       = (const float*)d_in[0];
    const int*   ei      = (const int*)d_in[1];
    const float* temb_in = (const float*)d_in[2];
    const int*   batch   = (const int*)d_in[3];
    const float* Wt      = (const float*)d_in[4];
    const float* bt      = (const float*)d_in[5];
    const float* W1      = (const float*)d_in[6];
    const float* b1      = (const float*)d_in[7];
    const float* Ws      = (const float*)d_in[8];
    const float* bs      = (const float*)d_in[9];
    const float* Wo      = (const float*)d_in[10];
    const float* bo      = (const float*)d_in[11];
    float* out = (float*)d_out;

    const int N = N_NODES, E = N_EDGES;
    const int* src = ei;
    const int* dst = ei + E;

    char* p = (char*)d_ws;
    auto carve = [&](size_t bytes) -> void* {
        void* r = (void*)p;
        p += (bytes + 255) & ~(size_t)255;
        return r;
    };
    int*    cnt     = (int*)carve((size_t)N * 4);
    float*  dinv    = (float*)carve((size_t)N * 4);
    int*    row_ptr = (int*)carve((size_t)(N + 1) * 4);
    int*    cursor  = (int*)carve((size_t)N * 4);
    int*    partial = (int*)carve((size_t)128 * 4);
    int2*   edge    = (int2*)carve((size_t)E * 8);
    int*    gstart  = (int*)carve((size_t)(N_GRAPHS + 1) * 4);
    ushort* packed  = (ushort*)carve((size_t)57344 * 2);
    ushort* xb      = (ushort*)carve((size_t)N * 64 * 2);
    ushort* tembb   = (ushort*)carve((size_t)N * 128 * 2);
    uchar*  H1f8    = (uchar*)carve((size_t)N * 128);       // conv1 out, fp8 e4m3
    ushort* H2      = (ushort*)carve((size_t)N * 128 * 2);
    ushort* H3      = (ushort*)carve((size_t)N * 128 * 2);

    const ushort* Wtp  = packed;
    const ushort* W1p  = packed + 16384;
    const ushort* Ws0p = packed + 24576;
    const ushort* Ws1p = packed + 40960;

    const int ntiles = N / 16;            // 6250
    const int gblk   = (ntiles + 3) / 4;  // 1563
    const int nb     = (N + 1023) / 1024; // 98

    // prep: cvt x | cvt temb | zero cnt | pack W | boundaries   (one launch)
    prep_kernel<<<10381, 256, 0, stream>>>(x, xb, temb_in, tembb, cnt, Wt, W1, Ws,
                                           packed, batch, gstart);

    // CSR build
    hist_kernel<<<(E / 4 + 255) / 256, 256, 0, stream>>>((const int4*)dst, cnt, E / 4);
    scanA<<<nb, 256, 0, stream>>>(cnt, row_ptr, partial, dinv, N);
    scanC<<<(N + 255) / 256, 256, 0, stream>>>(row_ptr, partial, cursor, N, nb);
    fill_kernel<<<(E + 255) / 256, 256, 0, stream>>>(src, dst, dinv, cursor, edge, E);

    // conv1 (+fused temb layer): H1f8 = relu(agg(x)@W1+b1) + relu(tembb@Wt+bt)
    fused_conv<64, true, false, true><<<gblk, 256, 0, stream>>>(
        xb, row_ptr, edge, dinv, W1p, b1, tembb, Wtp, bt, H1f8, ntiles);
    // conv2 (fp8 gather): H2 = relu(agg(H1f8)@Ws0 + bs0)
    fused_conv<128, false, true, false><<<gblk, 256, 0, stream>>>(
        H1f8, row_ptr, edge, dinv, Ws0p, bs, nullptr, nullptr, nullptr, H2, ntiles);
    // conv3: H3 = relu(agg(H2)@Ws1 + bs1)
    fused_conv<128, false, false, false><<<gblk, 256, 0, stream>>>(
        H2, row_ptr, edge, dinv, Ws1p, bs + 128, nullptr, nullptr, nullptr, H3, ntiles);

    // pool + head (fused)
    pool_out<<<N_GRAPHS, 256, 0, stream>>>(H3, gstart, Wo, bo, out);
}